// Round 2
// baseline (195.324 us; speedup 1.0000x reference)
//
#include <hip/hip_runtime.h>
#include <hip/hip_bf16.h>

typedef __bf16 bf16;
typedef __bf16 bf16x8 __attribute__((ext_vector_type(8)));
typedef __bf16 bf16x4 __attribute__((ext_vector_type(4)));
typedef float  f32x2  __attribute__((ext_vector_type(2)));
typedef float  f32x4  __attribute__((ext_vector_type(4)));
typedef float  f32x16 __attribute__((ext_vector_type(16)));

#define B_ 2
#define L_ 2048
#define E_ 1024
#define H_ 16
#define D_ 64

// XOR-swizzled LDS tile: 64 bf16 cols/row as 8 chunks of 8; conflict-free for
// both row-staging writes and column-ish frag reads.
__device__ __forceinline__ int swz(int r, int c) {
    return r * 64 + (((c ^ (r & 7)) & 7) << 3);
}

// async global->LDS DMA, 16B per lane; lds dest = wave-uniform base + lane*16
#define DMA16(gp, lp)                                                              \
    __builtin_amdgcn_global_load_lds(                                              \
        (const __attribute__((address_space(1))) unsigned int*)(gp),               \
        (__attribute__((address_space(3))) unsigned int*)(lp), 16, 0, 0)

// ---------------- fused prep: everything becomes pre-swizzled 8KB tiles ----------------
// [0,1024):    V [b][l][h][d] fp32 -> vt tiles [bh][kt][4096]  (V^T 64d x 64k,
//              k-cols sigma-permuted within each 16-group, swizzled)
// [1024,2048): mask i32 -> mtq2 [b][k>>5][q] u32. Bit order within each word:
//              bit (8c+lp) = mask at k = 32*kw + 4*lp + c  (int4-load/ballot layout)
// [2048,3072): K fp32 -> kt tiles [b][h][kt][4096] (64k x 64d, swizzled)
// [3072,3328): W fp32 -> wbt tiles [n6][kt][4096] (64n x 64k, swizzled)
__global__ __launch_bounds__(256) void prep_kernel(const float* __restrict__ v,
                                                   const float* __restrict__ keys,
                                                   const int* __restrict__ mask,
                                                   const float* __restrict__ W,
                                                   bf16* __restrict__ vt_,
                                                   bf16* __restrict__ kt_,
                                                   unsigned int* __restrict__ mtq2,
                                                   bf16* __restrict__ wbt) {
    __shared__ __attribute__((aligned(16))) float tile[64 * 65];
    const int bid = blockIdx.x;
    const int t = threadIdx.x;
    if (bid < 1024) {
        // V transpose + sigma-permute + swizzle
        int bh = bid >> 5, b = bh >> 4, h = bh & 15, kt = bid & 31;
        int kk = t >> 2, dg = t & 3;
        const float* src = v + (((size_t)(b * L_ + kt * 64 + kk)) * H_ + h) * D_ + dg * 16;
        float4 f[4];
#pragma unroll
        for (int i = 0; i < 4; i++) f[i] = reinterpret_cast<const float4*>(src)[i];
#pragma unroll
        for (int i = 0; i < 16; i++)
            tile[(dg * 16 + i) * 65 + kk] = reinterpret_cast<const float*>(f)[i];
        __syncthreads();
        int dd = t >> 2, cg = t & 3;
        const int sig[16] = {0, 1, 2, 3, 8, 9, 10, 11, 4, 5, 6, 7, 12, 13, 14, 15};
        bf16 tmp[16];
#pragma unroll
        for (int p = 0; p < 16; p++)
            tmp[p] = (bf16)tile[dd * 65 + cg * 16 + sig[p]];
        bf16* dst = vt_ + ((size_t)bh * 32 + kt) * 4096;
        *reinterpret_cast<uint4*>(dst + swz(dd, cg * 2))     = *reinterpret_cast<const uint4*>(&tmp[0]);
        *reinterpret_cast<uint4*>(dst + swz(dd, cg * 2 + 1)) = *reinterpret_cast<const uint4*>(&tmp[8]);
    } else if (bid < 2048) {
        // mask packing: int4 loads (16B/lane), 4 ballots/pass, 8 passes.
        // word kw, bit (8c+lp) <- mask[k = 32*kw + 4*lp + c]
        int idx = bid - 1024;
        int b = idx >> 9;
        int q = (idx & 511) * 4 + (t >> 6);
        int li = t & 63;
        const int* mrow = mask + ((size_t)b * L_ + q) * L_;
        unsigned int* mq = mtq2 + (size_t)b * 64 * 2048;
#pragma unroll 2
        for (int pass = 0; pass < 8; pass++) {
            int4 m4 = reinterpret_cast<const int4*>(mrow)[pass * 64 + li];
            unsigned long long b0 = __ballot(m4.x & 1);
            unsigned long long b1 = __ballot(m4.y & 1);
            unsigned long long b2 = __ballot(m4.z & 1);
            unsigned long long b3 = __ballot(m4.w & 1);
            if (li < 8) {
                unsigned int word = (unsigned int)((b0 >> (8 * li)) & 0xFFull)
                                  | ((unsigned int)((b1 >> (8 * li)) & 0xFFull) << 8)
                                  | ((unsigned int)((b2 >> (8 * li)) & 0xFFull) << 16)
                                  | ((unsigned int)((b3 >> (8 * li)) & 0xFFull) << 24);
                mq[(size_t)(pass * 8 + li) * 2048 + q] = word;
            }
        }
    } else if (bid < 3072) {
        int idx = bid - 2048;
        int b = idx >> 9, h = (idx >> 5) & 15, kt = idx & 31;
        int r = t >> 2, cg = t & 3;
        const float* src = keys + ((size_t)(b * L_ + kt * 64 + r)) * E_ + h * 64 + cg * 16;
        float4 f[4];
#pragma unroll
        for (int i = 0; i < 4; i++) f[i] = reinterpret_cast<const float4*>(src)[i];
        bf16 tmp[16];
#pragma unroll
        for (int i = 0; i < 16; i++)
            tmp[i] = (bf16)reinterpret_cast<const float*>(f)[i];
        bf16* dst = kt_ + ((size_t)(b * 16 + h) * 32 + kt) * 4096;
        *reinterpret_cast<uint4*>(dst + swz(r, cg * 2))     = *reinterpret_cast<const uint4*>(&tmp[0]);
        *reinterpret_cast<uint4*>(dst + swz(r, cg * 2 + 1)) = *reinterpret_cast<const uint4*>(&tmp[8]);
    } else {
        int idx = bid - 3072;
        int n6 = idx >> 4, kt = idx & 15;
        int r = t >> 2, cg = t & 3;
        const float* src = W + ((size_t)(n6 * 64 + r)) * E_ + kt * 64 + cg * 16;
        float4 f[4];
#pragma unroll
        for (int i = 0; i < 4; i++) f[i] = reinterpret_cast<const float4*>(src)[i];
        bf16 tmp[16];
#pragma unroll
        for (int i = 0; i < 16; i++)
            tmp[i] = (bf16)reinterpret_cast<const float*>(f)[i];
        bf16* dst = wbt + ((size_t)(n6 * 16 + kt)) * 4096;
        *reinterpret_cast<uint4*>(dst + swz(r, cg * 2))     = *reinterpret_cast<const uint4*>(&tmp[0]);
        *reinterpret_cast<uint4*>(dst + swz(r, cg * 2 + 1)) = *reinterpret_cast<const uint4*>(&tmp[8]);
    }
}

// ---------------- flash attention: pipelined (softmax/PV one tile late) ----------------
// Tq=64/block, Tk=64. 4 waves 2x2 (wq x wk): wave = 32q x 32k per ktile.
// Body kt: QK^T of tile kt + softmax/PV of tile kt-1 -> the softmax VALU chain
// never waits on the MFMA chain that feeds it (latency absorbed across the
// barrier). K double-buffered, V TRIPLE-buffered (PV reads V one body after its
// DMA); Q staging overlays V-buf2 (dead until DMA of tile 2). LDS = 40960
// -> 4 blocks/CU. Grid is (bh, qtile) so all 32 q-blocks of one bh share an
// XCD: per-XCD K/V working set 2MB fits the 4MB L2.
__global__ __launch_bounds__(256, 4) void attn_kernel(const float* __restrict__ q_,
                                                      const bf16* __restrict__ kt_,
                                                      const bf16* __restrict__ vt_,
                                                      const unsigned int* __restrict__ mtq2,
                                                      bf16* __restrict__ xbt) {
    __shared__ __attribute__((aligned(16))) char smem[40960];
    // layout: K0 [0,8K) K1 [8K,16K) V0 [16K,24K) V1 [24K,32K) V2/Qs [32K,40K)
    bf16* Qs = (bf16*)(smem + 32768);
    float* Om = (float*)smem;            // epilogue overlay [64d][64q]
    float* Lrow = (float*)(smem + 16384);
    bf16* Xs = (bf16*)(smem + 16896);    // [64][72]

    const int bh = blockIdx.x, b = bh >> 4, hd = bh & 15;
    const int q0 = blockIdx.y * 64;
    const int t = threadIdx.x;
    const int w = t >> 6, lane = t & 63, h = lane >> 5, l31 = lane & 31;
    const int wq = w & 1, wk = w >> 1;
    const int r_ = t >> 2, cg = t & 3;

    const float CSCALE = 1.4426950408889634f / 32.0f;  // log2(e)/sqrt(E)

    const bf16* kbase = kt_ + (size_t)bh * 32 * 4096;
    const bf16* vbase = vt_ + (size_t)bh * 32 * 4096;

    // DMA tile 0 -> K0, V0
    {
        const bf16* gk = kbase + w * 1024 + lane * 8;
        DMA16(gk, smem + w * 2048);
        DMA16(gk + 512, smem + w * 2048 + 1024);
        const bf16* gv = vbase + w * 1024 + lane * 8;
        DMA16(gv, smem + 16384 + w * 2048);
        DMA16(gv + 512, smem + 16384 + w * 2048 + 1024);
    }
    // stage Q (fp32 -> scaled bf16, swizzled) into V2 region (dead until tile2 DMA)
    {
        const float* src = q_ + ((size_t)(b * L_ + q0 + r_)) * E_ + hd * 64 + cg * 16;
        float4 f[4];
#pragma unroll
        for (int i = 0; i < 4; i++) f[i] = reinterpret_cast<const float4*>(src)[i];
        bf16 tmp[16];
#pragma unroll
        for (int i = 0; i < 16; i++)
            tmp[i] = (bf16)(reinterpret_cast<const float*>(f)[i] * CSCALE);
        *reinterpret_cast<uint4*>(&Qs[swz(r_, cg * 2)])     = *reinterpret_cast<const uint4*>(&tmp[0]);
        *reinterpret_cast<uint4*>(&Qs[swz(r_, cg * 2 + 1)]) = *reinterpret_cast<const uint4*>(&tmp[8]);
    }
    __syncthreads();  // Q visible; own-wave vmcnt(0) drained -> K0/V0 ready

    // block-stationary Q^T B-frags: n=q=l31, k-slots = d chunks dc*2+h
    bf16x8 bq[4];
#pragma unroll
    for (int dc = 0; dc < 4; dc++)
        bq[dc] = *reinterpret_cast<const bf16x8*>(&Qs[swz(wq * 32 + l31, dc * 2 + h)]);

    // DMA tile 1 -> K1, V1
    {
        const bf16* gk = kbase + 4096 + w * 1024 + lane * 8;
        DMA16(gk, smem + 8192 + w * 2048);
        DMA16(gk + 512, smem + 8192 + w * 2048 + 1024);
        const bf16* gv = vbase + 4096 + w * 1024 + lane * 8;
        DMA16(gv, smem + 24576 + w * 2048);
        DMA16(gv + 512, smem + 24576 + w * 2048 + 1024);
    }

    const unsigned int* mbase = mtq2 + (size_t)b * 64 * 2048 + q0 + wq * 32 + l31;
    unsigned int mwHeld = mbase[(size_t)wk * 2048];  // tile 0's word

    f32x16 oc[2] = {{}, {}};
    f32x2 ls = {0.0f, 0.0f};

    // QK of tile 0 (K0 ready after the barrier above)
    f32x16 st = {};
    {
        const bf16* Kc = (const bf16*)smem;
#pragma unroll
        for (int dc = 0; dc < 4; dc++) {
            bf16x8 ak = *reinterpret_cast<const bf16x8*>(&Kc[swz(wk * 32 + l31, dc * 2 + h)]);
            st = __builtin_amdgcn_mfma_f32_32x32x16_bf16(ak, bq[dc], st, 0, 0, 0);
        }
    }

    int vP = 16384, vC = 24576, vN = 32768;  // V buf byte offsets for tiles kt-1, kt, kt+1
    for (int kt = 1; kt < L_ / 64; kt++) {
        __syncthreads();  // implicit vmcnt(0): DMA(kt) complete; prior LDS reads drained
        const int koff = (kt & 1) << 13;
        if (kt + 1 < L_ / 64) {
            const int koffN = koff ^ 8192;
            const bf16* gk = kbase + (size_t)(kt + 1) * 4096 + w * 1024 + lane * 8;
            DMA16(gk, smem + koffN + w * 2048);
            DMA16(gk + 512, smem + koffN + w * 2048 + 1024);
            const bf16* gv = vbase + (size_t)(kt + 1) * 4096 + w * 1024 + lane * 8;
            DMA16(gv, smem + vN + w * 2048);
            DMA16(gv + 512, smem + vN + w * 2048 + 1024);
        }
        unsigned int mwN = mbase[(size_t)(kt * 2 + wk) * 2048];  // tile kt's word

        // early frag reads: K(kt) + V(kt-1); lgkm latency hidden under softmax
        const bf16* Kc = (const bf16*)(smem + koff);
        const bf16* Vp = (const bf16*)(smem + vP);
        bf16x8 ak[4], av[4];
#pragma unroll
        for (int dc = 0; dc < 4; dc++)
            ak[dc] = *reinterpret_cast<const bf16x8*>(&Kc[swz(wk * 32 + l31, dc * 2 + h)]);
#pragma unroll
        for (int j = 0; j < 4; j++) {
            const int da = j >> 1, kc = j & 1;
            av[j] = *reinterpret_cast<const bf16x8*>(&Vp[swz(da * 32 + l31, wk * 4 + kc * 2 + h)]);
        }

        // softmax of tile kt-1 (st ready; no MFMA dependency in this body)
        const unsigned int mwh = mwHeld >> h;
        float pv[16];
#pragma unroll
        for (int i = 0; i < 16; i += 2) {
            const int b0 = 8 * (i & 3) + 2 * (i >> 2);
            const int b1 = 8 * ((i + 1) & 3) + 2 * ((i + 1) >> 2);
            float e0 = __builtin_amdgcn_exp2f(st[i]);
            float e1 = __builtin_amdgcn_exp2f(st[i + 1]);
            int m0 = ((int)(mwh << (31 - b0))) >> 31;  // 0 or -1 (v_bfe_i32)
            int m1 = ((int)(mwh << (31 - b1))) >> 31;
            pv[i]     = __int_as_float(__float_as_int(e0) & m0);
            pv[i + 1] = __int_as_float(__float_as_int(e1) & m1);
            ls += (f32x2){pv[i], pv[i + 1]};           // v_pk_add_f32
        }
        bf16x8 bp[2];
#pragma unroll
        for (int kc = 0; kc < 2; kc++)
#pragma unroll
            for (int j = 0; j < 8; j++)
                bp[kc][j] = (bf16)pv[kc * 8 + j];

        __builtin_amdgcn_s_setprio(1);
        // QK of tile kt (st WAR on softmax above is program-ordered)
        st = (f32x16){};
#pragma unroll
        for (int dc = 0; dc < 4; dc++)
            st = __builtin_amdgcn_mfma_f32_32x32x16_bf16(ak[dc], bq[dc], st, 0, 0, 0);
        // PV of tile kt-1
#pragma unroll
        for (int j = 0; j < 4; j++) {
            const int da = j >> 1, kc = j & 1;
            oc[da] = __builtin_amdgcn_mfma_f32_32x32x16_bf16(av[j], bp[kc], oc[da], 0, 0, 0);
        }
        __builtin_amdgcn_s_setprio(0);

        mwHeld = mwN;
        int tmpv = vP; vP = vC; vC = vN; vN = tmpv;
    }

    // drain: softmax + PV of tile 31 (V(31) at vP after last rotation)
    {
        const unsigned int mwh = mwHeld >> h;
        float pv[16];
#pragma unroll
        for (int i = 0; i < 16; i += 2) {
            const int b0 = 8 * (i & 3) + 2 * (i >> 2);
            const int b1 = 8 * ((i + 1) & 3) + 2 * ((i + 1) >> 2);
            float e0 = __builtin_amdgcn_exp2f(st[i]);
            float e1 = __builtin_amdgcn_exp2f(st[i + 1]);
            int m0 = ((int)(mwh << (31 - b0))) >> 31;
            int m1 = ((int)(mwh << (31 - b1))) >> 31;
            pv[i]     = __int_as_float(__float_as_int(e0) & m0);
            pv[i + 1] = __int_as_float(__float_as_int(e1) & m1);
            ls += (f32x2){pv[i], pv[i + 1]};
        }
        bf16x8 bp[2];
#pragma unroll
        for (int kc = 0; kc < 2; kc++)
#pragma unroll
            for (int j = 0; j < 8; j++)
                bp[kc][j] = (bf16)pv[kc * 8 + j];
        const bf16* Vp = (const bf16*)(smem + vP);
#pragma unroll
        for (int j = 0; j < 4; j++) {
            const int da = j >> 1, kc = j & 1;
            bf16x8 av = *reinterpret_cast<const bf16x8*>(&Vp[swz(da * 32 + l31, wk * 4 + kc * 2 + h)]);
            oc[da] = __builtin_amdgcn_mfma_f32_32x32x16_bf16(av, bp[kc], oc[da], 0, 0, 0);
        }
    }
    __syncthreads();  // all reads of Ks/Vs done before epilogue overlays

    // merge wk partials (exact sum), divide, write swizzled x tile
    float lsum = ls.x + ls.y;
    float lw = lsum + __shfl(lsum, lane ^ 32, 64);
    if (wk == 1) {
#pragma unroll
        for (int da = 0; da < 2; da++)
#pragma unroll
            for (int i = 0; i < 16; i++) {
                int d = da * 32 + (i & 3) + 8 * (i >> 2) + 4 * h;
                Om[d * 64 + wq * 32 + l31] = oc[da][i];
            }
        if (h == 0) Lrow[wq * 32 + l31] = lw;
    }
    __syncthreads();
    if (wk == 0) {
        float rinv = 1.0f / (lw + Lrow[wq * 32 + l31]);
#pragma unroll
        for (int da = 0; da < 2; da++)
#pragma unroll
            for (int g = 0; g < 4; g++) {
                int d0 = da * 32 + 8 * g + 4 * h;
                bf16x4 pk;
#pragma unroll
                for (int r = 0; r < 4; r++)
                    pk[r] = (bf16)((oc[da][g * 4 + r] + Om[(d0 + r) * 64 + wq * 32 + l31]) * rinv);
                *reinterpret_cast<bf16x4*>(&Xs[(wq * 32 + l31) * 72 + d0]) = pk;
            }
    }
    __syncthreads();
    {
        bf16* xtile = xbt + ((size_t)((b * 32 + (q0 >> 6)) * 16 + hd)) * 4096;
        *reinterpret_cast<uint4*>(xtile + swz(r_, cg * 2))     = *reinterpret_cast<const uint4*>(&Xs[r_ * 72 + cg * 16]);
        *reinterpret_cast<uint4*>(xtile + swz(r_, cg * 2 + 1)) = *reinterpret_cast<const uint4*>(&Xs[r_ * 72 + cg * 16 + 8]);
    }
}

// ---------------- projection: out = x W^T + b ; 128x64 tiles, DMA double-buffer ----------------
__global__ __launch_bounds__(256, 3) void proj_kernel(const bf16* __restrict__ xbt,
                                                      const bf16* __restrict__ wbt,
                                                      const float* __restrict__ bias,
                                                      float* __restrict__ out) {
    __shared__ __attribute__((aligned(16))) char smem[49152];
    // As(p) = smem + p*16384 (2 tiles of 8KB) ; Bs(p) = smem + 32768 + p*8192
    const int n0 = blockIdx.x * 64, m0 = blockIdx.y * 128;
    const int t = threadIdx.x;
    const int w = t >> 6, lane = t & 63, h = lane >> 5, l31 = lane & 31;
    const int wm = w >> 1, wn = w & 1;

    const bf16* a0 = xbt + ((size_t)(m0 >> 6)) * 16 * 4096;       // tile row m6
    const bf16* a1 = a0 + 16 * 4096;                              // tile row m6+1
    const bf16* bb_ = wbt + ((size_t)(n0 >> 6)) * 16 * 4096;

    // DMA kt=0
    {
#pragma unroll
        for (int i = 0; i < 4; i++) {
            int c = w * 4 + i;  // 16 x 1KB chunks over A (2 tiles)
            const bf16* g = ((c >> 3) ? a1 : a0) + (c & 7) * 512 + lane * 8;
            DMA16(g, smem + c * 1024);
        }
#pragma unroll
        for (int i = 0; i < 2; i++) {
            int c = w * 2 + i;
            DMA16(bb_ + c * 512 + lane * 8, smem + 32768 + c * 1024);
        }
    }

    f32x16 acc[2] = {{}, {}};
    for (int kt = 0; kt < E_ / 64; kt++) {
        __syncthreads();
        bf16* Ac = (bf16*)(smem + (kt & 1) * 16384);
        bf16* Bc = (bf16*)(smem + 32768 + (kt & 1) * 8192);
        if (kt + 1 < E_ / 64) {
            char* An = smem + ((kt + 1) & 1) * 16384;
            char* Bn = smem + 32768 + ((kt + 1) & 1) * 8192;
            const bf16* an0 = a0 + (kt + 1) * 4096;
            const bf16* an1 = a1 + (kt + 1) * 4096;
            const bf16* bn = bb_ + (kt + 1) * 4096;
#pragma unroll
            for (int i = 0; i < 4; i++) {
                int c = w * 4 + i;
                const bf16* g = ((c >> 3) ? an1 : an0) + (c & 7) * 512 + lane * 8;
                DMA16(g, An + c * 1024);
            }
#pragma unroll
            for (int i = 0; i < 2; i++) {
                int c = w * 2 + i;
                DMA16(bn + c * 512 + lane * 8, Bn + c * 1024);
            }
        }
#pragma unroll
        for (int dc = 0; dc < 4; dc++) {
            bf16x8 bfr = *reinterpret_cast<const bf16x8*>(&Bc[swz(wn * 32 + l31, dc * 2 + h)]);
#pragma unroll
            for (int mi = 0; mi < 2; mi++) {
                bf16x8 afr = *reinterpret_cast<const bf16x8*>(&Ac[wm * 4096 + swz(mi * 32 + l31, dc * 2 + h)]);
                acc[mi] = __builtin_amdgcn_mfma_f32_32x32x16_bf16(afr, bfr, acc[mi], 0, 0, 0);
            }
        }
    }

    float bv = bias[n0 + wn * 32 + l31];
#pragma unroll
    for (int mi = 0; mi < 2; mi++)
#pragma unroll
        for (int i = 0; i < 16; i++) {
            int row = m0 + wm * 64 + mi * 32 + (i & 3) + 8 * (i >> 2) + 4 * h;
            out[(size_t)row * E_ + n0 + wn * 32 + l31] = acc[mi][i] + bv;
        }
}

extern "C" void kernel_launch(void* const* d_in, const int* in_sizes, int n_in,
                              void* d_out, int out_size, void* d_ws, size_t ws_size,
                              hipStream_t stream) {
    (void)in_sizes; (void)n_in; (void)out_size; (void)ws_size;
    const float* values = (const float*)d_in[0];
    const float* keys   = (const float*)d_in[1];
    const float* query  = (const float*)d_in[2];
    const int*   mask   = (const int*)d_in[3];
    const float* W_out  = (const float*)d_in[4];
    const float* b_out  = (const float*)d_in[5];
    float* out = (float*)d_out;

    char* ws = (char*)d_ws;
    bf16* vt_ = (bf16*)(ws);                               // 8 MB  V^T tiles [bh][kt][4096] (sigma-permuted, swizzled)
    bf16* kt_ = (bf16*)(ws + 8388608);                     // 8 MB  K tiles [b][h][kt][4096] (swizzled)
    bf16* wbt = (bf16*)(ws + 16777216);                    // 2 MB  W tiles [n6][kt][4096] (swizzled)
    unsigned int* mtq2 = (unsigned int*)(ws + 18874368);   // 1 MB  [b][k>>5][q] u32 (ballot-byte bit order)
    bf16* xbt = (bf16*)(ws + 19922944);                    // 8 MB  x tiles [m6][hd][4096] (swizzled)

    prep_kernel<<<3328, 256, 0, stream>>>(values, keys, mask, W_out, vt_, kt_, mtq2, wbt);
    // grid = (bh, qtile): all 32 q-blocks of a bh share linear%8 -> same XCD L2
    attn_kernel<<<dim3(B_ * H_, L_ / 64), 256, 0, stream>>>(query, kt_, vt_, mtq2, xbt);
    proj_kernel<<<dim3(E_ / 64, (B_ * L_) / 128), 256, 0, stream>>>(xbt, wbt, b_out, out);
}

// Round 3
// 193.715 us; speedup vs baseline: 1.0083x; 1.0083x over previous
//
#include <hip/hip_runtime.h>
#include <hip/hip_bf16.h>

typedef __bf16 bf16;
typedef __bf16 bf16x8 __attribute__((ext_vector_type(8)));
typedef __bf16 bf16x4 __attribute__((ext_vector_type(4)));
typedef float  f32x2  __attribute__((ext_vector_type(2)));
typedef float  f32x4  __attribute__((ext_vector_type(4)));
typedef float  f32x16 __attribute__((ext_vector_type(16)));

#define B_ 2
#define L_ 2048
#define E_ 1024
#define H_ 16
#define D_ 64

// XOR-swizzled LDS tile: 64 bf16 cols/row as 8 chunks of 8; conflict-free for
// both row-staging writes and column-ish frag reads.
__device__ __forceinline__ int swz(int r, int c) {
    return r * 64 + (((c ^ (r & 7)) & 7) << 3);
}

// async global->LDS DMA, 16B per lane; lds dest = wave-uniform base + lane*16
#define DMA16(gp, lp)                                                              \
    __builtin_amdgcn_global_load_lds(                                              \
        (const __attribute__((address_space(1))) unsigned int*)(gp),               \
        (__attribute__((address_space(3))) unsigned int*)(lp), 16, 0, 0)

// ---------------- fused prep: everything becomes pre-swizzled 8KB tiles ----------------
// [0,1024):    V [b][l][h][d] fp32 -> vt tiles [bh][kt][4096]  (V^T 64d x 64k,
//              k-cols sigma-permuted within each 16-group, swizzled)
// [1024,2048): mask i32 -> mtq2 [b][k>>5][q] u32. Bit order within each word:
//              bit (8c+lp) = mask at k = 32*kw + 4*lp + c  (int4-load/ballot layout)
// [2048,3072): K fp32 -> kt tiles [b][h][kt][4096] (64k x 64d, swizzled)
// [3072,3328): W fp32 -> wbt tiles [n6][kt][4096] (64n x 64k, swizzled)
__global__ __launch_bounds__(256) void prep_kernel(const float* __restrict__ v,
                                                   const float* __restrict__ keys,
                                                   const int* __restrict__ mask,
                                                   const float* __restrict__ W,
                                                   bf16* __restrict__ vt_,
                                                   bf16* __restrict__ kt_,
                                                   unsigned int* __restrict__ mtq2,
                                                   bf16* __restrict__ wbt) {
    __shared__ __attribute__((aligned(16))) float tile[64 * 65];
    const int bid = blockIdx.x;
    const int t = threadIdx.x;
    if (bid < 1024) {
        // V transpose + sigma-permute + swizzle
        int bh = bid >> 5, b = bh >> 4, h = bh & 15, kt = bid & 31;
        int kk = t >> 2, dg = t & 3;
        const float* src = v + (((size_t)(b * L_ + kt * 64 + kk)) * H_ + h) * D_ + dg * 16;
        float4 f[4];
#pragma unroll
        for (int i = 0; i < 4; i++) f[i] = reinterpret_cast<const float4*>(src)[i];
#pragma unroll
        for (int i = 0; i < 16; i++)
            tile[(dg * 16 + i) * 65 + kk] = reinterpret_cast<const float*>(f)[i];
        __syncthreads();
        int dd = t >> 2, cg = t & 3;
        const int sig[16] = {0, 1, 2, 3, 8, 9, 10, 11, 4, 5, 6, 7, 12, 13, 14, 15};
        bf16 tmp[16];
#pragma unroll
        for (int p = 0; p < 16; p++)
            tmp[p] = (bf16)tile[dd * 65 + cg * 16 + sig[p]];
        bf16* dst = vt_ + ((size_t)bh * 32 + kt) * 4096;
        *reinterpret_cast<uint4*>(dst + swz(dd, cg * 2))     = *reinterpret_cast<const uint4*>(&tmp[0]);
        *reinterpret_cast<uint4*>(dst + swz(dd, cg * 2 + 1)) = *reinterpret_cast<const uint4*>(&tmp[8]);
    } else if (bid < 2048) {
        // mask packing: int4 loads (16B/lane), 4 ballots/pass, 8 passes.
        // word kw, bit (8c+lp) <- mask[k = 32*kw + 4*lp + c]
        int idx = bid - 1024;
        int b = idx >> 9;
        int q = (idx & 511) * 4 + (t >> 6);
        int li = t & 63;
        const int* mrow = mask + ((size_t)b * L_ + q) * L_;
        unsigned int* mq = mtq2 + (size_t)b * 64 * 2048;
#pragma unroll 2
        for (int pass = 0; pass < 8; pass++) {
            int4 m4 = reinterpret_cast<const int4*>(mrow)[pass * 64 + li];
            unsigned long long b0 = __ballot(m4.x & 1);
            unsigned long long b1 = __ballot(m4.y & 1);
            unsigned long long b2 = __ballot(m4.z & 1);
            unsigned long long b3 = __ballot(m4.w & 1);
            if (li < 8) {
                unsigned int word = (unsigned int)((b0 >> (8 * li)) & 0xFFull)
                                  | ((unsigned int)((b1 >> (8 * li)) & 0xFFull) << 8)
                                  | ((unsigned int)((b2 >> (8 * li)) & 0xFFull) << 16)
                                  | ((unsigned int)((b3 >> (8 * li)) & 0xFFull) << 24);
                mq[(size_t)(pass * 8 + li) * 2048 + q] = word;
            }
        }
    } else if (bid < 3072) {
        int idx = bid - 2048;
        int b = idx >> 9, h = (idx >> 5) & 15, kt = idx & 31;
        int r = t >> 2, cg = t & 3;
        const float* src = keys + ((size_t)(b * L_ + kt * 64 + r)) * E_ + h * 64 + cg * 16;
        float4 f[4];
#pragma unroll
        for (int i = 0; i < 4; i++) f[i] = reinterpret_cast<const float4*>(src)[i];
        bf16 tmp[16];
#pragma unroll
        for (int i = 0; i < 16; i++)
            tmp[i] = (bf16)reinterpret_cast<const float*>(f)[i];
        bf16* dst = kt_ + ((size_t)(b * 16 + h) * 32 + kt) * 4096;
        *reinterpret_cast<uint4*>(dst + swz(r, cg * 2))     = *reinterpret_cast<const uint4*>(&tmp[0]);
        *reinterpret_cast<uint4*>(dst + swz(r, cg * 2 + 1)) = *reinterpret_cast<const uint4*>(&tmp[8]);
    } else {
        int idx = bid - 3072;
        int n6 = idx >> 4, kt = idx & 15;
        int r = t >> 2, cg = t & 3;
        const float* src = W + ((size_t)(n6 * 64 + r)) * E_ + kt * 64 + cg * 16;
        float4 f[4];
#pragma unroll
        for (int i = 0; i < 4; i++) f[i] = reinterpret_cast<const float4*>(src)[i];
        bf16 tmp[16];
#pragma unroll
        for (int i = 0; i < 16; i++)
            tmp[i] = (bf16)reinterpret_cast<const float*>(f)[i];
        bf16* dst = wbt + ((size_t)(n6 * 16 + kt)) * 4096;
        *reinterpret_cast<uint4*>(dst + swz(r, cg * 2))     = *reinterpret_cast<const uint4*>(&tmp[0]);
        *reinterpret_cast<uint4*>(dst + swz(r, cg * 2 + 1)) = *reinterpret_cast<const uint4*>(&tmp[8]);
    }
}

// ---------------- flash attention: 2-wave register-blocked (64q x 32k per wave) ----------------
// Tq=64/block, Tk=64, 128 threads = 2 waves, wave w owns k-half w (32 k-rows).
// Each wave holds BOTH q-half Q-frags in registers -> every K-frag read feeds
// 2 QK MFMAs, every V-frag feeds 2 PV MFMAs: LDS frag reads per block-ktile
// drop from 32KB to 16KB (= tile size, no amplification). 16 MFMA per
// wave-body. K/V double-buffered via DMA; single barrier per ktile.
// VGPR ~220 -> 2 waves/SIMD, 4 blocks/CU (LDS 40KB).
__global__ __launch_bounds__(128, 2) void attn_kernel(const float* __restrict__ q_,
                                                      const bf16* __restrict__ kt_,
                                                      const bf16* __restrict__ vt_,
                                                      const unsigned int* __restrict__ mtq2,
                                                      bf16* __restrict__ xbt) {
    __shared__ __attribute__((aligned(16))) char smem[40960];
    // K0 [0,8K) K1 [8K,16K) V0 [16K,24K) V1 [24K,32K) Qs [32K,40K)
    bf16* Qs = (bf16*)(smem + 32768);
    float* Om = (float*)smem;            // epilogue overlay [64d][64q]
    float* Lrow = (float*)(smem + 16384);
    bf16* Xs = (bf16*)(smem + 16896);    // [64][72]

    const int bh = blockIdx.y, b = bh >> 4, hd = bh & 15;
    const int q0 = blockIdx.x * 64;
    const int t = threadIdx.x;
    const int w = t >> 6, lane = t & 63, h = lane >> 5, l31 = lane & 31;
    const int r_ = t >> 1, half = t & 1;

    const float CSCALE = 1.4426950408889634f / 32.0f;  // log2(e)/sqrt(E)

    const bf16* kbase = kt_ + (size_t)bh * 32 * 4096;
    const bf16* vbase = vt_ + (size_t)bh * 32 * 4096;

    // DMA tile 0 -> K0, V0 (each wave stages 4KB of K + 4KB of V)
    {
        const bf16* gk = kbase + w * 2048 + lane * 8;
        const bf16* gv = vbase + w * 2048 + lane * 8;
#pragma unroll
        for (int i = 0; i < 4; i++) {
            DMA16(gk + i * 512, smem + w * 4096 + i * 1024);
            DMA16(gv + i * 512, smem + 16384 + w * 4096 + i * 1024);
        }
    }
    // stage Q (fp32 -> scaled bf16, swizzled); thread handles half a row (32 elems)
    {
        const float* src = q_ + ((size_t)(b * L_ + q0 + r_)) * E_ + hd * 64 + half * 32;
        float4 f[8];
#pragma unroll
        for (int i = 0; i < 8; i++) f[i] = reinterpret_cast<const float4*>(src)[i];
        bf16 tmp[32];
#pragma unroll
        for (int i = 0; i < 32; i++)
            tmp[i] = (bf16)(reinterpret_cast<const float*>(f)[i] * CSCALE);
#pragma unroll
        for (int j = 0; j < 4; j++)
            *reinterpret_cast<uint4*>(&Qs[swz(r_, half * 4 + j)]) =
                *reinterpret_cast<const uint4*>(&tmp[j * 8]);
    }
    __syncthreads();  // Q visible; own-wave vmcnt(0) drained -> K0/V0 ready

    // block-stationary Q^T B-frags for BOTH q-halves: n=q = qh*32+l31
    bf16x8 bq[2][4];
#pragma unroll
    for (int qh = 0; qh < 2; qh++)
#pragma unroll
        for (int dc = 0; dc < 4; dc++)
            bq[qh][dc] = *reinterpret_cast<const bf16x8*>(&Qs[swz(qh * 32 + l31, dc * 2 + h)]);

    f32x16 oc[2][2] = {{{}, {}}, {{}, {}}};  // [qh][da] O^T 64d x 64q (this wave's k-half)
    f32x2 ls[2] = {{0.0f, 0.0f}, {0.0f, 0.0f}};

    const unsigned int* mbase = mtq2 + (size_t)b * 64 * 2048 + q0 + l31;

    for (int kt = 0; kt < L_ / 64; kt++) {
        __syncthreads();  // implicit vmcnt(0): DMA for kt complete; prior reads of next buffer done
        const bf16* Kc = (const bf16*)(smem + (kt & 1) * 8192);
        const bf16* Vc = (const bf16*)(smem + 16384 + (kt & 1) * 8192);
        if (kt + 1 < L_ / 64) {
            char* Kn = smem + ((kt + 1) & 1) * 8192 + w * 4096;
            char* Vn = smem + 16384 + ((kt + 1) & 1) * 8192 + w * 4096;
            const bf16* gk = kbase + (size_t)(kt + 1) * 4096 + w * 2048 + lane * 8;
            const bf16* gv = vbase + (size_t)(kt + 1) * 4096 + w * 2048 + lane * 8;
#pragma unroll
            for (int i = 0; i < 4; i++) {
                DMA16(gk + i * 512, Kn + i * 1024);
                DMA16(gv + i * 512, Vn + i * 1024);
            }
        }
        // mask words for both q-halves (used ~300cy later; L2-resident)
        unsigned int mw0 = mbase[(size_t)(kt * 2 + w) * 2048];
        unsigned int mw1 = mbase[(size_t)(kt * 2 + w) * 2048 + 32];

        // frag reads: 4 K (own k-half) + 4 V (all d, own k-half) = 8KB/wave
        bf16x8 ak[4], av[4];
#pragma unroll
        for (int dc = 0; dc < 4; dc++)
            ak[dc] = *reinterpret_cast<const bf16x8*>(&Kc[swz(w * 32 + l31, dc * 2 + h)]);
#pragma unroll
        for (int j = 0; j < 4; j++) {
            const int da = j >> 1, kc = j & 1;
            av[j] = *reinterpret_cast<const bf16x8*>(&Vc[swz(da * 32 + l31, w * 4 + kc * 2 + h)]);
        }

        // S^T = K.Q^T for both q-halves: K-frag reused 2x
        f32x16 st[2] = {{}, {}};
        __builtin_amdgcn_s_setprio(1);
#pragma unroll
        for (int dc = 0; dc < 4; dc++) {
            st[0] = __builtin_amdgcn_mfma_f32_32x32x16_bf16(ak[dc], bq[0][dc], st[0], 0, 0, 0);
            st[1] = __builtin_amdgcn_mfma_f32_32x32x16_bf16(ak[dc], bq[1][dc], st[1], 0, 0, 0);
        }
        __builtin_amdgcn_s_setprio(0);

        // P = exp2(S^T) masked (bfe+and); pack both q-halves' B-operands
        bf16x8 bp[2][2];
#pragma unroll
        for (int qh = 0; qh < 2; qh++) {
            const unsigned int mwh = (qh ? mw1 : mw0) >> h;
            float pv[16];
#pragma unroll
            for (int i = 0; i < 16; i += 2) {
                const int b0 = 8 * (i & 3) + 2 * (i >> 2);
                const int b1 = 8 * ((i + 1) & 3) + 2 * ((i + 1) >> 2);
                float e0 = __builtin_amdgcn_exp2f(st[qh][i]);
                float e1 = __builtin_amdgcn_exp2f(st[qh][i + 1]);
                int m0 = ((int)(mwh << (31 - b0))) >> 31;  // 0 or -1 (v_bfe_i32)
                int m1 = ((int)(mwh << (31 - b1))) >> 31;
                pv[i]     = __int_as_float(__float_as_int(e0) & m0);
                pv[i + 1] = __int_as_float(__float_as_int(e1) & m1);
                ls[qh] += (f32x2){pv[i], pv[i + 1]};       // v_pk_add_f32
            }
#pragma unroll
            for (int kc = 0; kc < 2; kc++)
#pragma unroll
                for (int j = 0; j < 8; j++)
                    bp[qh][kc][j] = (bf16)pv[kc * 8 + j];
        }

        // O^T += V^T.P^T : V-frag reused 2x
        __builtin_amdgcn_s_setprio(1);
#pragma unroll
        for (int da = 0; da < 2; da++)
#pragma unroll
            for (int kc = 0; kc < 2; kc++) {
                oc[0][da] = __builtin_amdgcn_mfma_f32_32x32x16_bf16(av[da * 2 + kc], bp[0][kc], oc[0][da], 0, 0, 0);
                oc[1][da] = __builtin_amdgcn_mfma_f32_32x32x16_bf16(av[da * 2 + kc], bp[1][kc], oc[1][da], 0, 0, 0);
            }
        __builtin_amdgcn_s_setprio(0);
    }
    __syncthreads();  // all reads of Ks/Vs done before epilogue overlays

    // merge the two waves' k-half partials (exact sum), divide, write swizzled x tile
    float lw[2];
#pragma unroll
    for (int qh = 0; qh < 2; qh++) {
        float s = ls[qh].x + ls[qh].y;
        lw[qh] = s + __shfl(s, lane ^ 32, 64);  // merge h-halves (k-rows) within wave
    }
    if (w == 1) {
#pragma unroll
        for (int qh = 0; qh < 2; qh++)
#pragma unroll
            for (int da = 0; da < 2; da++)
#pragma unroll
                for (int i = 0; i < 16; i++) {
                    int d = da * 32 + (i & 3) + 8 * (i >> 2) + 4 * h;
                    Om[d * 64 + qh * 32 + l31] = oc[qh][da][i];
                }
        if (h == 0) {
            Lrow[l31] = lw[0];
            Lrow[32 + l31] = lw[1];
        }
    }
    __syncthreads();
    if (w == 0) {
#pragma unroll
        for (int qh = 0; qh < 2; qh++) {
            float rinv = 1.0f / (lw[qh] + Lrow[qh * 32 + l31]);
#pragma unroll
            for (int da = 0; da < 2; da++)
#pragma unroll
                for (int g = 0; g < 4; g++) {
                    int d0 = da * 32 + 8 * g + 4 * h;
                    bf16x4 pk;
#pragma unroll
                    for (int r = 0; r < 4; r++)
                        pk[r] = (bf16)((oc[qh][da][g * 4 + r] + Om[(d0 + r) * 64 + qh * 32 + l31]) * rinv);
                    *reinterpret_cast<bf16x4*>(&Xs[(qh * 32 + l31) * 72 + d0]) = pk;
                }
        }
    }
    __syncthreads();
    {
        bf16* xtile = xbt + ((size_t)((b * 32 + (q0 >> 6)) * 16 + hd)) * 4096;
#pragma unroll
        for (int j = 0; j < 4; j++) {
            int c = half * 4 + j;
            *reinterpret_cast<uint4*>(xtile + swz(r_, c)) =
                *reinterpret_cast<const uint4*>(&Xs[r_ * 72 + c * 8]);
        }
    }
}

// ---------------- projection: out = x W^T + b ; 128x64 tiles, DMA double-buffer ----------------
__global__ __launch_bounds__(256, 3) void proj_kernel(const bf16* __restrict__ xbt,
                                                      const bf16* __restrict__ wbt,
                                                      const float* __restrict__ bias,
                                                      float* __restrict__ out) {
    __shared__ __attribute__((aligned(16))) char smem[49152];
    // As(p) = smem + p*16384 (2 tiles of 8KB) ; Bs(p) = smem + 32768 + p*8192
    const int n0 = blockIdx.x * 64, m0 = blockIdx.y * 128;
    const int t = threadIdx.x;
    const int w = t >> 6, lane = t & 63, h = lane >> 5, l31 = lane & 31;
    const int wm = w >> 1, wn = w & 1;

    const bf16* a0 = xbt + ((size_t)(m0 >> 6)) * 16 * 4096;       // tile row m6
    const bf16* a1 = a0 + 16 * 4096;                              // tile row m6+1
    const bf16* bb_ = wbt + ((size_t)(n0 >> 6)) * 16 * 4096;

    // DMA kt=0
    {
#pragma unroll
        for (int i = 0; i < 4; i++) {
            int c = w * 4 + i;  // 16 x 1KB chunks over A (2 tiles)
            const bf16* g = ((c >> 3) ? a1 : a0) + (c & 7) * 512 + lane * 8;
            DMA16(g, smem + c * 1024);
        }
#pragma unroll
        for (int i = 0; i < 2; i++) {
            int c = w * 2 + i;
            DMA16(bb_ + c * 512 + lane * 8, smem + 32768 + c * 1024);
        }
    }

    f32x16 acc[2] = {{}, {}};
    for (int kt = 0; kt < E_ / 64; kt++) {
        __syncthreads();
        bf16* Ac = (bf16*)(smem + (kt & 1) * 16384);
        bf16* Bc = (bf16*)(smem + 32768 + (kt & 1) * 8192);
        if (kt + 1 < E_ / 64) {
            char* An = smem + ((kt + 1) & 1) * 16384;
            char* Bn = smem + 32768 + ((kt + 1) & 1) * 8192;
            const bf16* an0 = a0 + (kt + 1) * 4096;
            const bf16* an1 = a1 + (kt + 1) * 4096;
            const bf16* bn = bb_ + (kt + 1) * 4096;
#pragma unroll
            for (int i = 0; i < 4; i++) {
                int c = w * 4 + i;
                const bf16* g = ((c >> 3) ? an1 : an0) + (c & 7) * 512 + lane * 8;
                DMA16(g, An + c * 1024);
            }
#pragma unroll
            for (int i = 0; i < 2; i++) {
                int c = w * 2 + i;
                DMA16(bn + c * 512 + lane * 8, Bn + c * 1024);
            }
        }
#pragma unroll
        for (int dc = 0; dc < 4; dc++) {
            bf16x8 bfr = *reinterpret_cast<const bf16x8*>(&Bc[swz(wn * 32 + l31, dc * 2 + h)]);
#pragma unroll
            for (int mi = 0; mi < 2; mi++) {
                bf16x8 afr = *reinterpret_cast<const bf16x8*>(&Ac[wm * 4096 + swz(mi * 32 + l31, dc * 2 + h)]);
                acc[mi] = __builtin_amdgcn_mfma_f32_32x32x16_bf16(afr, bfr, acc[mi], 0, 0, 0);
            }
        }
    }

    float bv = bias[n0 + wn * 32 + l31];
#pragma unroll
    for (int mi = 0; mi < 2; mi++)
#pragma unroll
        for (int i = 0; i < 16; i++) {
            int row = m0 + wm * 64 + mi * 32 + (i & 3) + 8 * (i >> 2) + 4 * h;
            out[(size_t)row * E_ + n0 + wn * 32 + l31] = acc[mi][i] + bv;
        }
}

extern "C" void kernel_launch(void* const* d_in, const int* in_sizes, int n_in,
                              void* d_out, int out_size, void* d_ws, size_t ws_size,
                              hipStream_t stream) {
    (void)in_sizes; (void)n_in; (void)out_size; (void)ws_size;
    const float* values = (const float*)d_in[0];
    const float* keys   = (const float*)d_in[1];
    const float* query  = (const float*)d_in[2];
    const int*   mask   = (const int*)d_in[3];
    const float* W_out  = (const float*)d_in[4];
    const float* b_out  = (const float*)d_in[5];
    float* out = (float*)d_out;

    char* ws = (char*)d_ws;
    bf16* vt_ = (bf16*)(ws);                               // 8 MB  V^T tiles [bh][kt][4096] (sigma-permuted, swizzled)
    bf16* kt_ = (bf16*)(ws + 8388608);                     // 8 MB  K tiles [b][h][kt][4096] (swizzled)
    bf16* wbt = (bf16*)(ws + 16777216);                    // 2 MB  W tiles [n6][kt][4096] (swizzled)
    unsigned int* mtq2 = (unsigned int*)(ws + 18874368);   // 1 MB  [b][k>>5][q] u32 (ballot-byte bit order)
    bf16* xbt = (bf16*)(ws + 19922944);                    // 8 MB  x tiles [m6][hd][4096] (swizzled)

    prep_kernel<<<3328, 256, 0, stream>>>(values, keys, mask, W_out, vt_, kt_, mtq2, wbt);
    attn_kernel<<<dim3(L_ / 64, B_ * H_), 128, 0, stream>>>(query, kt_, vt_, mtq2, xbt);
    proj_kernel<<<dim3(E_ / 64, (B_ * L_) / 128), 256, 0, stream>>>(xbt, wbt, b_out, out);
}

// Round 4
// 191.657 us; speedup vs baseline: 1.0191x; 1.0107x over previous
//
#include <hip/hip_runtime.h>
#include <hip/hip_bf16.h>

typedef __bf16 bf16;
typedef __bf16 bf16x8 __attribute__((ext_vector_type(8)));
typedef __bf16 bf16x4 __attribute__((ext_vector_type(4)));
typedef float  f32x2  __attribute__((ext_vector_type(2)));
typedef float  f32x4  __attribute__((ext_vector_type(4)));
typedef float  f32x16 __attribute__((ext_vector_type(16)));

#define B_ 2
#define L_ 2048
#define E_ 1024
#define H_ 16
#define D_ 64

// XOR-swizzled LDS tile: 64 bf16 cols/row as 8 chunks of 8; conflict-free for
// both row-staging writes and column-ish frag reads.
__device__ __forceinline__ int swz(int r, int c) {
    return r * 64 + (((c ^ (r & 7)) & 7) << 3);
}

// async global->LDS DMA, 16B per lane; lds dest = wave-uniform base + lane*16
#define DMA16(gp, lp)                                                              \
    __builtin_amdgcn_global_load_lds(                                              \
        (const __attribute__((address_space(1))) unsigned int*)(gp),               \
        (__attribute__((address_space(3))) unsigned int*)(lp), 16, 0, 0)

// ---------------- fused prep: everything becomes pre-swizzled 8KB tiles ----------------
// [0,1024):    V [b][l][h][d] fp32 -> vt tiles [bh][kt][4096]  (V^T 64d x 64k,
//              k-cols sigma-permuted within each 16-group, swizzled)
// [1024,3072): mask i32 -> mbt bf16 bias tiles [b][qt][kt][4096]: [64k][64q],
//              value 0 (mask==1) or -512 (mask==0), swizzled. Consumed by attn
//              as MFMA A-fragments (S += M . I) - no per-score mask VALU.
// [3072,4096): K fp32 -> kt tiles [b][h][kt][4096] (64k x 64d, swizzled)
// [4096,4352): W fp32 -> wbt tiles [n6][kt][4096] (64n x 64k, swizzled)
__global__ __launch_bounds__(256) void prep_kernel(const float* __restrict__ v,
                                                   const float* __restrict__ keys,
                                                   const int* __restrict__ mask,
                                                   const float* __restrict__ W,
                                                   bf16* __restrict__ vt_,
                                                   bf16* __restrict__ kt_,
                                                   bf16* __restrict__ mbt,
                                                   bf16* __restrict__ wbt) {
    __shared__ __attribute__((aligned(16))) float tile[64 * 65];
    const int bid = blockIdx.x;
    const int t = threadIdx.x;
    if (bid < 1024) {
        // V transpose + sigma-permute + swizzle
        int bh = bid >> 5, b = bh >> 4, h = bh & 15, kt = bid & 31;
        int kk = t >> 2, dg = t & 3;
        const float* src = v + (((size_t)(b * L_ + kt * 64 + kk)) * H_ + h) * D_ + dg * 16;
        float4 f[4];
#pragma unroll
        for (int i = 0; i < 4; i++) f[i] = reinterpret_cast<const float4*>(src)[i];
#pragma unroll
        for (int i = 0; i < 16; i++)
            tile[(dg * 16 + i) * 65 + kk] = reinterpret_cast<const float*>(f)[i];
        __syncthreads();
        int dd = t >> 2, cg = t & 3;
        const int sig[16] = {0, 1, 2, 3, 8, 9, 10, 11, 4, 5, 6, 7, 12, 13, 14, 15};
        bf16 tmp[16];
#pragma unroll
        for (int p = 0; p < 16; p++)
            tmp[p] = (bf16)tile[dd * 65 + cg * 16 + sig[p]];
        bf16* dst = vt_ + ((size_t)bh * 32 + kt) * 4096;
        *reinterpret_cast<uint4*>(dst + swz(dd, cg * 2))     = *reinterpret_cast<const uint4*>(&tmp[0]);
        *reinterpret_cast<uint4*>(dst + swz(dd, cg * 2 + 1)) = *reinterpret_cast<const uint4*>(&tmp[8]);
    } else if (bid < 3072) {
        // mask -> bf16 bias tile [64k][64q], transposed via LDS, swizzled out.
        int idx = bid - 1024;
        int b = idx >> 10, qt = (idx >> 5) & 31, kt = idx & 31;
        unsigned short* Lt = (unsigned short*)tile;  // [64][72] u16
        int q = t >> 2, kc = t & 3;
        const int* mrow = mask + ((size_t)b * L_ + qt * 64 + q) * L_ + kt * 64 + kc * 16;
        int4 m4[4];
#pragma unroll
        for (int i = 0; i < 4; i++) m4[i] = reinterpret_cast<const int4*>(mrow)[i];
#pragma unroll
        for (int i = 0; i < 16; i++)
            Lt[(kc * 16 + i) * 72 + q] =
                (reinterpret_cast<const int*>(m4)[i] & 1) ? (unsigned short)0x0000
                                                          : (unsigned short)0xC400;  // bf16 -512
        __syncthreads();
        int r = t >> 2, cg = t & 3;
        unsigned short tmp[16];
#pragma unroll
        for (int i = 0; i < 16; i++) tmp[i] = Lt[r * 72 + cg * 16 + i];
        bf16* dst = mbt + ((size_t)((b * 32 + qt) * 32) + kt) * 4096;
        *reinterpret_cast<uint4*>(dst + swz(r, cg * 2))     = *reinterpret_cast<const uint4*>(&tmp[0]);
        *reinterpret_cast<uint4*>(dst + swz(r, cg * 2 + 1)) = *reinterpret_cast<const uint4*>(&tmp[8]);
    } else if (bid < 4096) {
        int idx = bid - 3072;
        int b = idx >> 9, h = (idx >> 5) & 15, kt = idx & 31;
        int r = t >> 2, cg = t & 3;
        const float* src = keys + ((size_t)(b * L_ + kt * 64 + r)) * E_ + h * 64 + cg * 16;
        float4 f[4];
#pragma unroll
        for (int i = 0; i < 4; i++) f[i] = reinterpret_cast<const float4*>(src)[i];
        bf16 tmp[16];
#pragma unroll
        for (int i = 0; i < 16; i++)
            tmp[i] = (bf16)reinterpret_cast<const float*>(f)[i];
        bf16* dst = kt_ + ((size_t)(b * 16 + h) * 32 + kt) * 4096;
        *reinterpret_cast<uint4*>(dst + swz(r, cg * 2))     = *reinterpret_cast<const uint4*>(&tmp[0]);
        *reinterpret_cast<uint4*>(dst + swz(r, cg * 2 + 1)) = *reinterpret_cast<const uint4*>(&tmp[8]);
    } else {
        int idx = bid - 4096;
        int n6 = idx >> 4, kt = idx & 15;
        int r = t >> 2, cg = t & 3;
        const float* src = W + ((size_t)(n6 * 64 + r)) * E_ + kt * 64 + cg * 16;
        float4 f[4];
#pragma unroll
        for (int i = 0; i < 4; i++) f[i] = reinterpret_cast<const float4*>(src)[i];
        bf16 tmp[16];
#pragma unroll
        for (int i = 0; i < 16; i++)
            tmp[i] = (bf16)reinterpret_cast<const float*>(f)[i];
        bf16* dst = wbt + ((size_t)(n6 * 16 + kt)) * 4096;
        *reinterpret_cast<uint4*>(dst + swz(r, cg * 2))     = *reinterpret_cast<const uint4*>(&tmp[0]);
        *reinterpret_cast<uint4*>(dst + swz(r, cg * 2 + 1)) = *reinterpret_cast<const uint4*>(&tmp[8]);
    }
}

// ---------------- flash attention: mask folded into MFMA ----------------
// Tq=64/block, Tk=64. 4 waves 2x2 (wq x wk): wave = 32q x 32k per ktile.
// S^T = M + K.Q^T: the mask bias (0/-512 bf16 tile) enters as 2 extra MFMAs
// against a constant identity B-frag -> softmax is pure exp2/cvt/pk_add
// (no bit extraction, no mask loads). exp2(-512+s) == 0.0 exactly, so results
// are identical to the bit-mask path. K/V double-buffered; M single-buffered
// (early frag read + 2nd barrier). Q staging overlays the M region.
// LDS 40KB -> 4 blocks/CU (grid-capped at 16 waves/CU).
__global__ __launch_bounds__(256, 4) void attn_kernel(const float* __restrict__ q_,
                                                      const bf16* __restrict__ kt_,
                                                      const bf16* __restrict__ vt_,
                                                      const bf16* __restrict__ mbt,
                                                      bf16* __restrict__ xbt) {
    __shared__ __attribute__((aligned(16))) char smem[40960];
    // K0 [0,8K) K1 [8K,16K) V0 [16K,24K) V1 [24K,32K) M/Qs [32K,40K)
    bf16* Qs = (bf16*)(smem + 32768);
    float* Om = (float*)smem;            // epilogue overlay [64d][64q]
    float* Lrow = (float*)(smem + 16384);
    bf16* Xs = (bf16*)(smem + 16896);    // [64][72]

    const int bh = blockIdx.y, b = bh >> 4, hd = bh & 15;
    const int q0 = blockIdx.x * 64;
    const int t = threadIdx.x;
    const int w = t >> 6, lane = t & 63, h = lane >> 5, l31 = lane & 31;
    const int wq = w & 1, wk = w >> 1;
    const int r_ = t >> 2, cg = t & 3;

    const float CSCALE = 1.4426950408889634f / 32.0f;  // log2(e)/sqrt(E)

    const bf16* kbase = kt_ + (size_t)bh * 32 * 4096;
    const bf16* vbase = vt_ + (size_t)bh * 32 * 4096;
    const bf16* mbase = mbt + (size_t)((b * 32 + (q0 >> 6)) * 32) * 4096;

    // DMA tile 0 -> K0, V0 (2KB per wave per tensor)
    {
        const bf16* gk = kbase + w * 1024 + lane * 8;
        DMA16(gk, smem + w * 2048);
        DMA16(gk + 512, smem + w * 2048 + 1024);
        const bf16* gv = vbase + w * 1024 + lane * 8;
        DMA16(gv, smem + 16384 + w * 2048);
        DMA16(gv + 512, smem + 16384 + w * 2048 + 1024);
    }
    // stage Q (fp32 -> scaled bf16, swizzled) into the M region (dead until M0 DMA)
    {
        const float* src = q_ + ((size_t)(b * L_ + q0 + r_)) * E_ + hd * 64 + cg * 16;
        float4 f[4];
#pragma unroll
        for (int i = 0; i < 4; i++) f[i] = reinterpret_cast<const float4*>(src)[i];
        bf16 tmp[16];
#pragma unroll
        for (int i = 0; i < 16; i++)
            tmp[i] = (bf16)(reinterpret_cast<const float*>(f)[i] * CSCALE);
        *reinterpret_cast<uint4*>(&Qs[swz(r_, cg * 2)])     = *reinterpret_cast<const uint4*>(&tmp[0]);
        *reinterpret_cast<uint4*>(&Qs[swz(r_, cg * 2 + 1)]) = *reinterpret_cast<const uint4*>(&tmp[8]);
    }
    __syncthreads();  // Q visible; own-wave vmcnt(0) drained -> K0/V0 ready

    // block-stationary Q^T B-frags: n=q=l31, k-slots = d chunks dc*2+h
    bf16x8 bq[4];
#pragma unroll
    for (int dc = 0; dc < 4; dc++)
        bq[dc] = *reinterpret_cast<const bf16x8*>(&Qs[swz(wq * 32 + l31, dc * 2 + h)]);
    __syncthreads();  // all bq reads landed -> M region reusable

    // DMA M(0) into the M region
    {
        const bf16* gm = mbase + w * 1024 + lane * 8;
        DMA16(gm, smem + 32768 + w * 2048);
        DMA16(gm + 512, smem + 32768 + w * 2048 + 1024);
    }

    // constant identity B-frags for the mask MFMAs: B_c[j][q] = (c*16+j == q)
    bf16x8 bi0, bi1;
    {
        const int i0 = l31 - h * 8;       // c = 0
        uint u0 = (i0 == 0) ? 0x00003F80u : (i0 == 1) ? 0x3F800000u : 0u;
        uint u1 = (i0 == 2) ? 0x00003F80u : (i0 == 3) ? 0x3F800000u : 0u;
        uint u2 = (i0 == 4) ? 0x00003F80u : (i0 == 5) ? 0x3F800000u : 0u;
        uint u3 = (i0 == 6) ? 0x00003F80u : (i0 == 7) ? 0x3F800000u : 0u;
        uint4 uu = {u0, u1, u2, u3};
        bi0 = *reinterpret_cast<bf16x8*>(&uu);
        const int i1 = l31 - 16 - h * 8;  // c = 1
        u0 = (i1 == 0) ? 0x00003F80u : (i1 == 1) ? 0x3F800000u : 0u;
        u1 = (i1 == 2) ? 0x00003F80u : (i1 == 3) ? 0x3F800000u : 0u;
        u2 = (i1 == 4) ? 0x00003F80u : (i1 == 5) ? 0x3F800000u : 0u;
        u3 = (i1 == 6) ? 0x00003F80u : (i1 == 7) ? 0x3F800000u : 0u;
        uint4 uu1 = {u0, u1, u2, u3};
        bi1 = *reinterpret_cast<bf16x8*>(&uu1);
    }

    f32x16 oc[2] = {{}, {}};
    f32x2 ls = {0.0f, 0.0f};

    for (int kt = 0; kt < L_ / 64; kt++) {
        __syncthreads();  // A: DMA(kt) complete (K,V,M); prior reads of next K/V buffer done
        const bf16* Kc = (const bf16*)(smem + (kt & 1) * 8192);
        const bf16* Vc = (const bf16*)(smem + 16384 + (kt & 1) * 8192);
        const bf16* Mc = (const bf16*)(smem + 32768);
        // early M frag reads (single-buffered region about to be re-DMA'd)
        bf16x8 am0 = *reinterpret_cast<const bf16x8*>(&Mc[swz(wk * 32 + l31, wq * 4 + 0 + h)]);
        bf16x8 am1 = *reinterpret_cast<const bf16x8*>(&Mc[swz(wk * 32 + l31, wq * 4 + 2 + h)]);
        __syncthreads();  // B: all M reads landed (lgkm drained per-wave at barrier)
        if (kt + 1 < L_ / 64) {
            char* Kn = smem + ((kt + 1) & 1) * 8192;
            char* Vn = smem + 16384 + ((kt + 1) & 1) * 8192;
            const bf16* gk = kbase + (size_t)(kt + 1) * 4096 + w * 1024 + lane * 8;
            DMA16(gk, Kn + w * 2048);
            DMA16(gk + 512, Kn + w * 2048 + 1024);
            const bf16* gv = vbase + (size_t)(kt + 1) * 4096 + w * 1024 + lane * 8;
            DMA16(gv, Vn + w * 2048);
            DMA16(gv + 512, Vn + w * 2048 + 1024);
            const bf16* gm = mbase + (size_t)(kt + 1) * 4096 + w * 1024 + lane * 8;
            DMA16(gm, smem + 32768 + w * 2048);
            DMA16(gm + 512, smem + 32768 + w * 2048 + 1024);
        }

        // S^T = M + K.Q^T : mask bias via 2 MFMAs against identity B
        f32x16 st = {};
        __builtin_amdgcn_s_setprio(1);
        st = __builtin_amdgcn_mfma_f32_32x32x16_bf16(am0, bi0, st, 0, 0, 0);
        st = __builtin_amdgcn_mfma_f32_32x32x16_bf16(am1, bi1, st, 0, 0, 0);
#pragma unroll
        for (int dc = 0; dc < 4; dc++) {
            bf16x8 ak = *reinterpret_cast<const bf16x8*>(&Kc[swz(wk * 32 + l31, dc * 2 + h)]);
            st = __builtin_amdgcn_mfma_f32_32x32x16_bf16(ak, bq[dc], st, 0, 0, 0);
        }
        __builtin_amdgcn_s_setprio(0);

        // P = exp2(S^T): masked entries are exp2(<=-500) == 0.0 exactly
        bf16x8 bp[2];
#pragma unroll
        for (int i = 0; i < 16; i += 2) {
            float e0 = __builtin_amdgcn_exp2f(st[i]);
            float e1 = __builtin_amdgcn_exp2f(st[i + 1]);
            ls += (f32x2){e0, e1};  // v_pk_add_f32
            bp[i >> 3][i & 7] = (bf16)e0;
            bp[(i + 1) >> 3][(i + 1) & 7] = (bf16)e1;
        }

        // O^T += V^T.P^T
        __builtin_amdgcn_s_setprio(1);
#pragma unroll
        for (int da = 0; da < 2; da++)
#pragma unroll
            for (int kc = 0; kc < 2; kc++) {
                bf16x8 av = *reinterpret_cast<const bf16x8*>(&Vc[swz(da * 32 + l31, wk * 4 + kc * 2 + h)]);
                oc[da] = __builtin_amdgcn_mfma_f32_32x32x16_bf16(av, bp[kc], oc[da], 0, 0, 0);
            }
        __builtin_amdgcn_s_setprio(0);
    }
    __syncthreads();  // all reads of Ks/Vs done before epilogue overlays

    // merge wk partials (exact sum), divide, write swizzled x tile
    float lsum = ls.x + ls.y;
    float lw = lsum + __shfl(lsum, lane ^ 32, 64);
    if (wk == 1) {
#pragma unroll
        for (int da = 0; da < 2; da++)
#pragma unroll
            for (int i = 0; i < 16; i++) {
                int d = da * 32 + (i & 3) + 8 * (i >> 2) + 4 * h;
                Om[d * 64 + wq * 32 + l31] = oc[da][i];
            }
        if (h == 0) Lrow[wq * 32 + l31] = lw;
    }
    __syncthreads();
    if (wk == 0) {
        float rinv = 1.0f / (lw + Lrow[wq * 32 + l31]);
#pragma unroll
        for (int da = 0; da < 2; da++)
#pragma unroll
            for (int g = 0; g < 4; g++) {
                int d0 = da * 32 + 8 * g + 4 * h;
                bf16x4 pk;
#pragma unroll
                for (int r = 0; r < 4; r++)
                    pk[r] = (bf16)((oc[da][g * 4 + r] + Om[(d0 + r) * 64 + wq * 32 + l31]) * rinv);
                *reinterpret_cast<bf16x4*>(&Xs[(wq * 32 + l31) * 72 + d0]) = pk;
            }
    }
    __syncthreads();
    {
        bf16* xtile = xbt + ((size_t)((b * 32 + (q0 >> 6)) * 16 + hd)) * 4096;
        *reinterpret_cast<uint4*>(xtile + swz(r_, cg * 2))     = *reinterpret_cast<const uint4*>(&Xs[r_ * 72 + cg * 16]);
        *reinterpret_cast<uint4*>(xtile + swz(r_, cg * 2 + 1)) = *reinterpret_cast<const uint4*>(&Xs[r_ * 72 + cg * 16 + 8]);
    }
}

// ---------------- projection: out = x W^T + b ; 128x64 tiles, DMA double-buffer ----------------
__global__ __launch_bounds__(256, 3) void proj_kernel(const bf16* __restrict__ xbt,
                                                      const bf16* __restrict__ wbt,
                                                      const float* __restrict__ bias,
                                                      float* __restrict__ out) {
    __shared__ __attribute__((aligned(16))) char smem[49152];
    // As(p) = smem + p*16384 (2 tiles of 8KB) ; Bs(p) = smem + 32768 + p*8192
    const int n0 = blockIdx.x * 64, m0 = blockIdx.y * 128;
    const int t = threadIdx.x;
    const int w = t >> 6, lane = t & 63, h = lane >> 5, l31 = lane & 31;
    const int wm = w >> 1, wn = w & 1;

    const bf16* a0 = xbt + ((size_t)(m0 >> 6)) * 16 * 4096;       // tile row m6
    const bf16* a1 = a0 + 16 * 4096;                              // tile row m6+1
    const bf16* bb_ = wbt + ((size_t)(n0 >> 6)) * 16 * 4096;

    // DMA kt=0
    {
#pragma unroll
        for (int i = 0; i < 4; i++) {
            int c = w * 4 + i;  // 16 x 1KB chunks over A (2 tiles)
            const bf16* g = ((c >> 3) ? a1 : a0) + (c & 7) * 512 + lane * 8;
            DMA16(g, smem + c * 1024);
        }
#pragma unroll
        for (int i = 0; i < 2; i++) {
            int c = w * 2 + i;
            DMA16(bb_ + c * 512 + lane * 8, smem + 32768 + c * 1024);
        }
    }

    f32x16 acc[2] = {{}, {}};
    for (int kt = 0; kt < E_ / 64; kt++) {
        __syncthreads();
        bf16* Ac = (bf16*)(smem + (kt & 1) * 16384);
        bf16* Bc = (bf16*)(smem + 32768 + (kt & 1) * 8192);
        if (kt + 1 < E_ / 64) {
            char* An = smem + ((kt + 1) & 1) * 16384;
            char* Bn = smem + 32768 + ((kt + 1) & 1) * 8192;
            const bf16* an0 = a0 + (kt + 1) * 4096;
            const bf16* an1 = a1 + (kt + 1) * 4096;
            const bf16* bn = bb_ + (kt + 1) * 4096;
#pragma unroll
            for (int i = 0; i < 4; i++) {
                int c = w * 4 + i;
                const bf16* g = ((c >> 3) ? an1 : an0) + (c & 7) * 512 + lane * 8;
                DMA16(g, An + c * 1024);
            }
#pragma unroll
            for (int i = 0; i < 2; i++) {
                int c = w * 2 + i;
                DMA16(bn + c * 512 + lane * 8, Bn + c * 1024);
            }
        }
#pragma unroll
        for (int dc = 0; dc < 4; dc++) {
            bf16x8 bfr = *reinterpret_cast<const bf16x8*>(&Bc[swz(wn * 32 + l31, dc * 2 + h)]);
#pragma unroll
            for (int mi = 0; mi < 2; mi++) {
                bf16x8 afr = *reinterpret_cast<const bf16x8*>(&Ac[wm * 4096 + swz(mi * 32 + l31, dc * 2 + h)]);
                acc[mi] = __builtin_amdgcn_mfma_f32_32x32x16_bf16(afr, bfr, acc[mi], 0, 0, 0);
            }
        }
    }

    float bv = bias[n0 + wn * 32 + l31];
#pragma unroll
    for (int mi = 0; mi < 2; mi++)
#pragma unroll
        for (int i = 0; i < 16; i++) {
            int row = m0 + wm * 64 + mi * 32 + (i & 3) + 8 * (i >> 2) + 4 * h;
            out[(size_t)row * E_ + n0 + wn * 32 + l31] = acc[mi][i] + bv;
        }
}

extern "C" void kernel_launch(void* const* d_in, const int* in_sizes, int n_in,
                              void* d_out, int out_size, void* d_ws, size_t ws_size,
                              hipStream_t stream) {
    (void)in_sizes; (void)n_in; (void)out_size; (void)ws_size;
    const float* values = (const float*)d_in[0];
    const float* keys   = (const float*)d_in[1];
    const float* query  = (const float*)d_in[2];
    const int*   mask   = (const int*)d_in[3];
    const float* W_out  = (const float*)d_in[4];
    const float* b_out  = (const float*)d_in[5];
    float* out = (float*)d_out;

    char* ws = (char*)d_ws;
    bf16* vt_ = (bf16*)(ws);                               // 8 MB   V^T tiles [bh][kt][4096] (sigma-permuted, swizzled)
    bf16* kt_ = (bf16*)(ws + 8388608);                     // 8 MB   K tiles [b][h][kt][4096] (swizzled)
    bf16* wbt = (bf16*)(ws + 16777216);                    // 2 MB   W tiles [n6][kt][4096] (swizzled)
    bf16* mbt = (bf16*)(ws + 18874368);                    // 16 MB  mask-bias tiles [b][qt][kt][4096] (swizzled)
    bf16* xbt = (bf16*)(ws + 35651584);                    // 8 MB   x tiles [m6][hd][4096] (swizzled)

    prep_kernel<<<4352, 256, 0, stream>>>(values, keys, mask, W_out, vt_, kt_, mbt, wbt);
    attn_kernel<<<dim3(L_ / 64, B_ * H_), 256, 0, stream>>>(query, kt_, vt_, mbt, xbt);
    proj_kernel<<<dim3(E_ / 64, (B_ * L_) / 128), 256, 0, stream>>>(xbt, wbt, b_out, out);
}